// Round 8
// baseline (75090.228 us; speedup 1.0000x reference)
//
#include <hip/hip_runtime.h>
#include <stdint.h>
#include <math.h>

// Persistent barrier-free 2-layer LSTM rollout, MI355X (gfx950).
// R8: ONE poll per step, SPLIT publishes.
//  - h1 buffer  [2][512]  slots {f16 h1[2w], f16 h1[2w+1] | u32 tag=t}, parity t&1.
//    Published right after the fused gate chain (early).
//  - cand buffer [2][1024] slots {f16 h0c|s=0, f16 h0c|s=1 | u32 tag=t}, parity t&1.
//    Published at end of shadow (late) -- off the critical chain.
// Iteration t: poll {h1(t-1), cands(t)} together -> z=W2.h1 -> s(t-1)
// (identical on every wave) -> select h0(t) -> 8 fused rows
// (Wih1@h0 + Whh1@h1) -> cell1 -> publish h1(t).
// Shadow: a0=Whh0@h0(t), candidate cells, publish cands(t+1), RNG, logp.
// R3's proven sleep-paced stale-only re-poll discipline throughout.

#define H     1024
#define NSTEP 8192
#define NWG   512
#define BLK   64
#define NROW  25   // 0-7 Wih1, 8-15 Whh0, 16-23 Whh1, 24 W2

typedef _Float16 h2 __attribute__((ext_vector_type(2)));
typedef _Float16 h8 __attribute__((ext_vector_type(8)));
typedef unsigned long long u64;

union U32H2 { uint32_t u; h2 v; };

__device__ __forceinline__ u64 pack2(float v0, float v1, uint32_t tag){
  U32H2 p; p.v.x = (_Float16)v0; p.v.y = (_Float16)v1;
  return ((u64)tag << 32) | (u64)p.u;
}

// Exact JAX threefry2x32.
__device__ __forceinline__ uint2 tf2x32(uint32_t k0, uint32_t k1, uint32_t x0, uint32_t x1){
  uint32_t k2 = k0 ^ k1 ^ 0x1BD11BDAu;
  x0 += k0; x1 += k1;
#define TFR(r) { x0 += x1; x1 = (x1 << (r)) | (x1 >> (32 - (r))); x1 ^= x0; }
  TFR(13) TFR(15) TFR(26) TFR(6)
  x0 += k1; x1 += k2 + 1u;
  TFR(17) TFR(29) TFR(16) TFR(24)
  x0 += k2; x1 += k0 + 2u;
  TFR(13) TFR(15) TFR(26) TFR(6)
  x0 += k0; x1 += k1 + 3u;
  TFR(17) TFR(29) TFR(16) TFR(24)
  x0 += k1; x1 += k2 + 4u;
  TFR(13) TFR(15) TFR(26) TFR(6)
  x0 += k2; x1 += k0 + 5u;
#undef TFR
  uint2 r; r.x = x0; r.y = x1; return r;
}

// keys = threefry_split(key(42), 8192)
__device__ __forceinline__ uint32_t jax_word(uint32_t i){
  return (i < 8192u) ? tf2x32(0u, 42u, i, i + 8192u).x
                     : tf2x32(0u, 42u, i - 8192u, i).y;
}

__device__ __forceinline__ float wred64(float x){
  #pragma unroll
  for(int off = 32; off > 0; off >>= 1) x += __shfl_xor(x, off, 64);
  return x;
}

// Merge-tree reduce of 8 per-lane partials over 64 lanes; results broadcast.
__device__ __forceinline__ void mreduce8(int lane, const float* v, float* s){
  const bool b1 = lane & 1;
  float t, w0, w1, w2, w3;
  t = b1 ? v[0] : v[1]; w0 = (b1 ? v[1] : v[0]) + __shfl_xor(t, 1, 64);
  t = b1 ? v[2] : v[3]; w1 = (b1 ? v[3] : v[2]) + __shfl_xor(t, 1, 64);
  t = b1 ? v[4] : v[5]; w2 = (b1 ? v[5] : v[4]) + __shfl_xor(t, 1, 64);
  t = b1 ? v[6] : v[7]; w3 = (b1 ? v[7] : v[6]) + __shfl_xor(t, 1, 64);
  const bool b2 = lane & 2;
  float u0, u1;
  t = b2 ? w0 : w1; u0 = (b2 ? w1 : w0) + __shfl_xor(t, 2, 64);
  t = b2 ? w2 : w3; u1 = (b2 ? w3 : w2) + __shfl_xor(t, 2, 64);
  const bool b4 = lane & 4;
  t = b4 ? u0 : u1; float z = (b4 ? u1 : u0) + __shfl_xor(t, 4, 64);
  z += __shfl_xor(z, 8, 64);
  z += __shfl_xor(z, 16, 64);
  z += __shfl_xor(z, 32, 64);
  #pragma unroll
  for(int r = 0; r < 8; r++) s[r] = __shfl(z, r, 64);
}

#if __has_builtin(__builtin_amdgcn_fdot2)
__device__ __forceinline__ float fdot2f(h2 a, h2 b, float c){ return __builtin_amdgcn_fdot2(a, b, c, false); }
#else
__device__ __forceinline__ float fdot2f(h2 a, h2 b, float c){
  return (float)a.x * (float)b.x + (float)a.y * (float)b.y + c;
}
#endif

__device__ __forceinline__ float sigm(float x){
  x = fminf(fmaxf(x, -30.f), 30.f);
  return 1.f / (1.f + __expf(-x));
}
__device__ __forceinline__ float tanh_f(float x){
  x = fminf(fmaxf(x, -15.f), 15.f);
  float e = __expf(2.f * x);
  return (e - 1.f) / (e + 1.f);
}

__device__ __forceinline__ u64 ld_slot(const u64* p){
  return __hip_atomic_load((u64*)p, __ATOMIC_RELAXED, __HIP_MEMORY_SCOPE_AGENT);
}
__device__ __forceinline__ void st_slot(u64* p, u64 v){
  __hip_atomic_store(p, v, __ATOMIC_RELAXED, __HIP_MEMORY_SCOPE_AGENT);
}

// One-wait poll of h1 slots (8, tag tagh) + cand slots (16, tag tagc).
// Initial full sweep, then sleep-paced stale-only re-sweeps.
template<bool WITH_H1>
__device__ __forceinline__ void poll_step(const u64* __restrict__ rh,
                                          const u64* __restrict__ rc,
                                          uint32_t tagh, uint32_t tagc,
                                          int lane, u64* pv, u64* cv){
  const u64* hA = rh + (lane << 2);
  const u64* hB = rh + 256 + (lane << 2);
  const u64* cA = rc + (lane << 3);
  const u64* cB = rc + 512 + (lane << 3);
  if(WITH_H1){
    #pragma unroll
    for(int k = 0; k < 4; k++){ pv[k] = ld_slot(hA + k); pv[4+k] = ld_slot(hB + k); }
  }
  #pragma unroll
  for(int k = 0; k < 8; k++){ cv[k] = ld_slot(cA + k); cv[8+k] = ld_slot(cB + k); }
  for(;;){
    uint32_t bad = 0;
    if(WITH_H1){
      #pragma unroll
      for(int k = 0; k < 8; k++) bad |= ((uint32_t)(pv[k] >> 32)) ^ tagh;
    }
    #pragma unroll
    for(int k = 0; k < 16; k++) bad |= ((uint32_t)(cv[k] >> 32)) ^ tagc;
    if(!bad) break;
    __builtin_amdgcn_s_sleep(1);
    if(WITH_H1){
      #pragma unroll
      for(int k = 0; k < 4; k++){
        if(((uint32_t)(pv[k]   >> 32)) != tagh) pv[k]   = ld_slot(hA + k);
        if(((uint32_t)(pv[4+k] >> 32)) != tagh) pv[4+k] = ld_slot(hB + k);
      }
    }
    #pragma unroll
    for(int k = 0; k < 8; k++){
      if(((uint32_t)(cv[k]   >> 32)) != tagc) cv[k]   = ld_slot(cA + k);
      if(((uint32_t)(cv[8+k] >> 32)) != tagc) cv[8+k] = ld_slot(cB + k);
    }
  }
}

__device__ __forceinline__ void extract_h1(const u64* pv, h2* f_h1){
  #pragma unroll
  for(int k = 0; k < 8; k++){ U32H2 p; p.u = (uint32_t)pv[k]; f_h1[k] = p.v; }
}

// Select h0 fragment from cand slots: sh = 0 (s=0) or 16 (s=1).
__device__ __forceinline__ void sel_cand(const u64* cv, uint32_t sh, h2* hv0){
  #pragma unroll
  for(int m = 0; m < 8; m++){
    uint32_t lo = (((uint32_t)cv[2*m])     >> sh) & 0xffffu;
    uint32_t hi = (((uint32_t)cv[2*m + 1]) >> sh) & 0xffffu;
    U32H2 p; p.u = lo | (hi << 16); hv0[m] = p.v;
  }
}

// Row dot partial: lane l covers h2 [4l,4l+4) and [256+4l,+4).
__device__ __forceinline__ float row_part(const h2* __restrict__ wrow, int lane, const h2* hv){
  h8 wl = *(const h8*)(wrow + (lane << 2));
  h8 wh = *(const h8*)(wrow + 256 + (lane << 2));
  float a0 = 0.f, a1 = 0.f;
  h2 w;
  w = __builtin_shufflevector(wl, wl, 0, 1); a0 = fdot2f(w, hv[0], a0);
  w = __builtin_shufflevector(wl, wl, 2, 3); a1 = fdot2f(w, hv[1], a1);
  w = __builtin_shufflevector(wl, wl, 4, 5); a0 = fdot2f(w, hv[2], a0);
  w = __builtin_shufflevector(wl, wl, 6, 7); a1 = fdot2f(w, hv[3], a1);
  w = __builtin_shufflevector(wh, wh, 0, 1); a0 = fdot2f(w, hv[4], a0);
  w = __builtin_shufflevector(wh, wh, 2, 3); a1 = fdot2f(w, hv[5], a1);
  w = __builtin_shufflevector(wh, wh, 4, 5); a0 = fdot2f(w, hv[6], a0);
  w = __builtin_shufflevector(wh, wh, 6, 7); a1 = fdot2f(w, hv[7], a1);
  return a0 + a1;
}

__global__ void __launch_bounds__(BLK)
lstm_persist(const float* __restrict__ ctx,  const float* __restrict__ W1p,  const float* __restrict__ b1p,
             const float* __restrict__ Wih0, const float* __restrict__ Whh0,
             const float* __restrict__ bih0, const float* __restrict__ bhh0,
             const float* __restrict__ Wih1, const float* __restrict__ Whh1,
             const float* __restrict__ bih1, const float* __restrict__ bhh1,
             const float* __restrict__ W2p,  const float* __restrict__ b2p,
             float* __restrict__ out,
             u64* __restrict__ h1b,   // [2][512]  h1 slots, parity t&1
             u64* __restrict__ cb)    // [2][1024] cand slots, parity t&1
{
  __shared__ h2 w[NROW][H/2];   // 51.2 KB; 2 WGs/CU co-resident

  const int lane = threadIdx.x;
  const int wg   = blockIdx.x;
  const int j0   = wg << 1;

  // ---- one-time: stage 25 rows as f16 (coalesced float4 reads)
  #pragma unroll 1
  for(int r = 0; r < NROW; r++){
    const float* rowp;
    if(r < 8)      { int g = r & 3,  j = j0 + (r >> 2);                   rowp = Wih1 + (size_t)(g*H + j)*H; }
    else if(r < 16){ int rr = r - 8;  int g = rr & 3, j = j0 + (rr >> 2); rowp = Whh0 + (size_t)(g*H + j)*H; }
    else if(r < 24){ int rr = r - 16; int g = rr & 3, j = j0 + (rr >> 2); rowp = Whh1 + (size_t)(g*H + j)*H; }
    else           rowp = W2p;
    const float4* s4 = (const float4*)rowp;
    #pragma unroll
    for(int it = 0; it < 4; it++){
      float4 f = s4[lane + (it << 6)];
      h2 pa; pa.x = (_Float16)f.x; pa.y = (_Float16)f.y;
      h2 pb; pb.x = (_Float16)f.z; pb.y = (_Float16)f.w;
      const int ci = (lane + (it << 6)) << 1;
      w[r][ci] = pa; w[r][ci + 1] = pb;
    }
  }
  __syncthreads();

  // per-wave scalars (uniform)
  float b0g[8], b1g[8], w0g[8];
  #pragma unroll
  for(int e = 0; e < 2; e++){
    const int j = j0 + e;
    #pragma unroll
    for(int g = 0; g < 4; g++){
      b0g[4*e + g] = bih0[g*H + j] + bhh0[g*H + j];
      b1g[4*e + g] = bih1[g*H + j] + bhh1[g*H + j];
      w0g[4*e + g] = Wih0[g*H + j];
    }
  }
  const float b2v = b2p[0];

  // x0 = W1 @ context + b1
  float xacc = 0.f;
  for(int c = lane; c < 512; c += 64) xacc += W1p[c] * ctx[c];
  const float x0 = wred64(xacc) + b1p[0];

  float c0v[2], c1v[2] = {0.f, 0.f}, logp = 0.f;
  float c0c[2][2];
  float ubatch = 1.f;
  u64 pv[8], cv[16];
  h2 f_h1[8], hv0[8];

  // ======== bootstrap: cands(0) (s-independent), then iteration t=0 ========
  {
    u64 pk[2];
    #pragma unroll
    for(int e = 0; e < 2; e++){
      float gi = sigm (w0g[4*e+0]*x0 + b0g[4*e+0]);
      float gg = tanh_f(w0g[4*e+2]*x0 + b0g[4*e+2]);
      float go = sigm (w0g[4*e+3]*x0 + b0g[4*e+3]);
      float cc = gi * gg;
      c0c[e][0] = c0c[e][1] = cc;
      float h00 = go * tanh_f(cc);
      pk[e] = pack2(h00, h00, 0u);
    }
    if(lane < 2) st_slot(&cb[j0 + lane], pk[lane]);
  }
  // iteration t=0: h1(-1)=0; s unused (cands equal); gates; publish h1(0); shadow
  {
    poll_step<false>(h1b, cb, 0u, 0u, lane, pv, cv);
    #pragma unroll
    for(int k = 0; k < 8; k++){ h2 zz; zz.x = (_Float16)0.f; zz.y = (_Float16)0.f; f_h1[k] = zz; }
    sel_cand(cv, 0u, hv0);
    c0v[0] = c0c[0][0]; c0v[1] = c0c[1][0];

    float pr[8], s1[8];
    #pragma unroll
    for(int r = 0; r < 8; r++) pr[r] = row_part(&w[r][0], lane, hv0);
    mreduce8(lane, pr, s1);
    float h1v[2];
    #pragma unroll
    for(int e = 0; e < 2; e++){
      float gi = sigm (s1[4*e+0] + b1g[4*e+0]);
      float gf = sigm (s1[4*e+1] + b1g[4*e+1]);
      float gg = tanh_f(s1[4*e+2] + b1g[4*e+2]);
      float go = sigm (s1[4*e+3] + b1g[4*e+3]);
      c1v[e] = gf*c1v[e] + gi*gg;
      h1v[e] = go * tanh_f(c1v[e]);
    }
    if(lane == 0) st_slot(&h1b[wg], pack2(h1v[0], h1v[1], 0u));

    // shadow: a0 rows, candidate cells, publish cands(1)
    float a0p[8], a0[8];
    #pragma unroll
    for(int r = 0; r < 8; r++) a0p[r] = row_part(&w[8 + r][0], lane, hv0);
    mreduce8(lane, a0p, a0);
    float h0c[2][2];
    #pragma unroll
    for(int e = 0; e < 2; e++){
      #pragma unroll
      for(int sb2 = 0; sb2 < 2; sb2++){
        const float sv = (float)sb2;
        float gi = sigm (a0[4*e+0] + w0g[4*e+0]*sv + b0g[4*e+0]);
        float gf = sigm (a0[4*e+1] + w0g[4*e+1]*sv + b0g[4*e+1]);
        float gg = tanh_f(a0[4*e+2] + w0g[4*e+2]*sv + b0g[4*e+2]);
        float go = sigm (a0[4*e+3] + w0g[4*e+3]*sv + b0g[4*e+3]);
        float cc = gf*c0v[e] + gi*gg;
        c0c[e][sb2] = cc;
        h0c[e][sb2] = go * tanh_f(cc);
      }
    }
    if(lane < 2)
      st_slot(&cb[1024 + j0 + lane],
              lane ? pack2(h0c[1][0], h0c[1][1], 1u) : pack2(h0c[0][0], h0c[0][1], 1u));
  }

  // ======== main loop t = 1..NSTEP ========
  #pragma unroll 1
  for(int t = 1; t <= NSTEP; t++){
    const u64* rh = h1b + (((t - 1) & 1) << 9);
    const u64* rc = cb  + ((t & 1) << 10);

    poll_step<true>(rh, rc, (uint32_t)(t - 1), (uint32_t)t, lane, pv, cv);
    extract_h1(pv, f_h1);

    // s(t-1): z = W2 . h1(t-1) (identical on all waves)
    float z = row_part(&w[24][0], lane, f_h1);
    z = wred64(z) + b2v;
    const float p = sigm(z);
    const int idx = t - 1;
    if((idx & 63) == 0){
      const uint32_t i0 = (uint32_t)idx + (uint32_t)lane;
      const uint32_t kk0 = jax_word(2u*i0), kk1 = jax_word(2u*i0 + 1u);
      const uint32_t bits = tf2x32(kk0, kk1, 0u, 0u).x;
      ubatch = __uint_as_float((bits >> 9) | 0x3f800000u) - 1.0f;
    }
    const float u = __shfl(ubatch, idx & 63, 64);
    const bool  sb_ = (u < p);

    if(t == NSTEP){
      logp += sb_ ? __logf(p) : __logf(1.f - p);
      if(wg == 0 && lane == 0){ out[NSTEP - 1] = sb_ ? 1.f : 0.f; out[NSTEP] = logp; }
      break;
    }

    // select h0(t); fused gates; publish h1(t)  [the only on-chain compute]
    sel_cand(cv, sb_ ? 16u : 0u, hv0);
    c0v[0] = sb_ ? c0c[0][1] : c0c[0][0];
    c0v[1] = sb_ ? c0c[1][1] : c0c[1][0];

    float pr[8], s1[8];
    #pragma unroll
    for(int r = 0; r < 8; r++)
      pr[r] = row_part(&w[r][0], lane, hv0) + row_part(&w[16 + r][0], lane, f_h1);
    mreduce8(lane, pr, s1);
    float h1v[2];
    #pragma unroll
    for(int e = 0; e < 2; e++){
      float gi = sigm (s1[4*e+0] + b1g[4*e+0]);
      float gf = sigm (s1[4*e+1] + b1g[4*e+1]);
      float gg = tanh_f(s1[4*e+2] + b1g[4*e+2]);
      float go = sigm (s1[4*e+3] + b1g[4*e+3]);
      c1v[e] = gf*c1v[e] + gi*gg;
      h1v[e] = go * tanh_f(c1v[e]);
    }
    if(lane == 0) st_slot(&h1b[((t & 1) << 9) + wg], pack2(h1v[0], h1v[1], (uint32_t)t));

    // ---- shadow: logp/out, a0 rows, candidate cells, publish cands(t+1)
    logp += sb_ ? __logf(p) : __logf(1.f - p);
    if(wg == 0 && lane == 0) out[t - 1] = sb_ ? 1.f : 0.f;

    float a0p[8], a0[8];
    #pragma unroll
    for(int r = 0; r < 8; r++) a0p[r] = row_part(&w[8 + r][0], lane, hv0);
    mreduce8(lane, a0p, a0);

    float h0c[2][2];
    #pragma unroll
    for(int e = 0; e < 2; e++){
      #pragma unroll
      for(int sb2 = 0; sb2 < 2; sb2++){
        const float sv = (float)sb2;
        float gi = sigm (a0[4*e+0] + w0g[4*e+0]*sv + b0g[4*e+0]);
        float gf = sigm (a0[4*e+1] + w0g[4*e+1]*sv + b0g[4*e+1]);
        float gg = tanh_f(a0[4*e+2] + w0g[4*e+2]*sv + b0g[4*e+2]);
        float go = sigm (a0[4*e+3] + w0g[4*e+3]*sv + b0g[4*e+3]);
        float cc = gf*c0v[e] + gi*gg;
        c0c[e][sb2] = cc;
        h0c[e][sb2] = go * tanh_f(cc);
      }
    }
    if(lane < 2)
      st_slot(&cb[(((t + 1) & 1) << 10) + j0 + lane],
              lane ? pack2(h0c[1][0], h0c[1][1], (uint32_t)(t + 1))
                   : pack2(h0c[0][0], h0c[0][1], (uint32_t)(t + 1)));
  }
}

extern "C" void kernel_launch(void* const* d_in, const int* in_sizes, int n_in,
                              void* d_out, int out_size, void* d_ws, size_t ws_size,
                              hipStream_t stream){
  u64* h1b = (u64*)d_ws;          // [2][512]  = 8 KB
  u64* cb  = h1b + 1024;          // [2][1024] = 16 KB
  hipLaunchKernelGGL(lstm_persist, dim3(NWG), dim3(BLK), 0, stream,
    (const float*)d_in[0],  (const float*)d_in[1],  (const float*)d_in[2],
    (const float*)d_in[3],  (const float*)d_in[4],  (const float*)d_in[5],  (const float*)d_in[6],
    (const float*)d_in[7],  (const float*)d_in[8],  (const float*)d_in[9],  (const float*)d_in[10],
    (const float*)d_in[11], (const float*)d_in[12],
    (float*)d_out, h1b, cb);
}